// Round 7
// baseline (1042.237 us; speedup 1.0000x reference)
//
#include <hip/hip_runtime.h>
#include <cfloat>

#define B_  8
#define N_  2048
#define H_  256
#define L_  4
#define K_  16
#define G_  512
#define M0_ 256
#define M1_ 128
#define C_  128
#define BN_ 16384   // B_*N_
#define KP_ 768     // effective split-bf16 K (3*H_)
#define KPC_ 512    // compact pack row stride [hi(0:256) | lo(256:512)]

typedef unsigned short ushort_t;
typedef __attribute__((ext_vector_type(8))) short short8;
typedef __attribute__((ext_vector_type(4))) float f32x4;

// ---------------- workspace layout (bytes) ----------------
// shared fixed region
#define OFF_H     ((size_t)0)            // 16 MB   h (fp32, persistent)
#define OFF_APACK ((size_t)16777216)     // 16.8 MB compact P-pack [hi|lo]
#define OFF_WPK   ((size_t)33554432)     // 3.93 MB all weight packs (3840 x 512 bf16)
#define OFF_BCA   ((size_t)37486592)     // 8 KB    bcat arena
#define OFF_STA   ((size_t)37494784)     // 36 KB   stats arena (9 x 512 doubles)
#define OFF_SQ    ((size_t)37531648)     // 64 KB
#define OFF_IDX   ((size_t)37597184)     // 1 MB -> ends 38,645,760
// big path: uv gets its own home (so it can be written concurrently with D)
#define OFF_UVBIG ((size_t)38645760)     // 33.5 MB -> ends 72,200,192
#define OFF_DSML  ((size_t)69206016)     // small path D (uv/t/pmax overlay inside)
#define OFF_DBIG  ((size_t)72200192)     // big path D
#define WS_SMALL  ((size_t)203423744)    // OFF_DSML + 134,217,728
#define WS_BIG    ((size_t)206417920)    // OFF_DBIG + 134,217,728

// weight-pack arena row offsets
#define WPK_WNN   0
#define WPK_WL    256      // + l*256
#define WPK_WG    1280
#define WPK_QCAT  1792     // + l*512

// ---------------- helpers ----------------
static __device__ __forceinline__ ushort_t f2bf(float f) {
    unsigned u = __float_as_uint(f);
    unsigned r = (u + 0x7fffu + ((u >> 16) & 1u)) >> 16;   // RNE
    return (ushort_t)r;
}
static __device__ __forceinline__ float bf2f(ushort_t h) {
    return __uint_as_float(((unsigned)h) << 16);
}
// segment remaps on the compact [hi|lo] pack.
// A-side effective order [hi,lo,hi]; B-side effective order [hi,hi,lo].
static __device__ __forceinline__ int kmapA(int k0) { return (k0 < KPC_) ? k0 : k0 - KPC_; }
static __device__ __forceinline__ int kmapB(int k0) { return (k0 < 256)  ? k0 : k0 - 256; }

// ---------------- fused prep: feat_pack + pack_all + stats zero ----------------
__global__ void prep(const float* __restrict__ x, const float* __restrict__ Wf,
                     const float* __restrict__ bfv, float* __restrict__ h,
                     ushort_t* __restrict__ Ap,
                     const float* __restrict__ Wnn, const float* __restrict__ Wl,
                     const float* __restrict__ Wg, const float* __restrict__ We,
                     const float* __restrict__ be, ushort_t* __restrict__ Qp,
                     float* __restrict__ bcat, double* __restrict__ sta) {
    int blk = blockIdx.x;
    int tid = threadIdx.x;
    if (blk < BN_) {
        int pt = blk, f = tid;
        float x0 = x[pt * 3 + 0], x1 = x[pt * 3 + 1], x2 = x[pt * 3 + 2];
        float v = x0 * Wf[f] + x1 * Wf[H_ + f] + x2 * Wf[2 * H_ + f] + bfv[f];
        h[(size_t)pt * H_ + f] = v;
        ushort_t hi = f2bf(v), lo = f2bf(v - bf2f(hi));
        size_t base = (size_t)pt * KPC_;
        Ap[base + f] = hi; Ap[base + H_ + f] = lo;
    } else if (blk < BN_ + 3840) {
        int row = blk - BN_, k = tid;
        float w;
        if (row < 1792) {
            const float* W; int Nd, n;
            if (row < 256)        { W = Wnn; Nd = 256; n = row; }
            else if (row < 1280)  { int l = (row - 256) >> 8;
                                    W = Wl + (size_t)l * (H_ * H_); Nd = 256; n = (row - 256) & 255; }
            else                  { W = Wg; Nd = 512; n = row - 1280; }
            w = W[(size_t)k * Nd + n];
        } else {
            int rr = row - 1792; int l = rr >> 9; int n = rr & 511;
            const float* We_l = We + (size_t)l * 2 * H_ * H_;
            if (n < H_) w = We_l[(size_t)k * H_ + n] - We_l[(size_t)H_ * H_ + (size_t)k * H_ + n];
            else        w = We_l[(size_t)H_ * H_ + (size_t)k * H_ + (n - H_)];
            if (k == 0) bcat[l * 512 + n] = (n < H_) ? be[l * H_ + n] : 0.f;
        }
        ushort_t hi = f2bf(w), lo = f2bf(w - bf2f(hi));
        size_t base = (size_t)row * KPC_;
        Qp[base + k] = hi; Qp[base + H_ + k] = lo;
    } else {
        int slot = blk - (BN_ + 3840);
        sta[(size_t)slot * 512 + tid] = 0.0;
        sta[(size_t)slot * 512 + 256 + tid] = 0.0;
    }
}

// ---- split-bf16 MFMA GEMM core (compact packs, K=768 via remaps) ----
// mode 0: out[r][c] = acc + aux[c]
// mode 2: out[r][c] = resid[r][c] + alphap[aidx]*(acc+aux[c])
// stats != nullptr: accumulate per-column sum/sumsq of written values
// nx != 0: 1-D grid of nx*128 blocks, XCD-pinned: z=blk&7 owns batch z's rows.
__global__ __launch_bounds__(256) void mfma_gemm(
    const ushort_t* __restrict__ P, const ushort_t* __restrict__ Q,
    const float* __restrict__ aux, float* __restrict__ out,
    int ldOut, int mode, const float* __restrict__ resid,
    const float* __restrict__ alphap, int aidx, double* __restrict__ stats,
    int nx) {
    __shared__ __align__(16) ushort_t As[128 * 32];
    __shared__ __align__(16) ushort_t Bs[128 * 32];
    __shared__ float cs1[4][64], cs2[4][64];
    int i0, j0;
    if (nx) {
        int blk = blockIdx.x;
        int z = blk & 7;
        int rest = blk >> 3;
        int xb = rest % nx;
        int ys = rest / nx;            // 0..15
        i0 = (z * 16 + ys) * 128;
        j0 = xb * 128;
    } else {
        i0 = blockIdx.y * 128; j0 = blockIdx.x * 128;
    }
    int tid = threadIdx.x;
    int lane = tid & 63, wave = tid >> 6;
    int wm = wave & 1, wn = wave >> 1;
    int m16 = lane & 15, kq = (lane >> 4) * 8;

    f32x4 acc[4][4];
    f32x4 zero = {0.f, 0.f, 0.f, 0.f};
#pragma unroll
    for (int i = 0; i < 4; ++i)
#pragma unroll
        for (int j = 0; j < 4; ++j) acc[i][j] = zero;

    int srow = tid >> 2;
    int skc  = (tid & 3) * 8;

    for (int k0 = 0; k0 < KP_; k0 += 32) {
        int ka = kmapA(k0), kb = kmapB(k0);
#pragma unroll
        for (int s = 0; s < 2; ++s) {
            int row = srow + s * 64;
            const ushort_t* gpA = P + (size_t)(i0 + row) * KPC_ + ka + skc;
            const ushort_t* gpB = Q + (size_t)(j0 + row) * KPC_ + kb + skc;
            __builtin_amdgcn_global_load_lds(
                (const __attribute__((address_space(1))) void*)gpA,
                (__attribute__((address_space(3))) void*)(As + (size_t)(wave * 64 + s * 256) * 8),
                16, 0, 0);
            __builtin_amdgcn_global_load_lds(
                (const __attribute__((address_space(1))) void*)gpB,
                (__attribute__((address_space(3))) void*)(Bs + (size_t)(wave * 64 + s * 256) * 8),
                16, 0, 0);
        }
        __syncthreads();
        short8 af[4], bfr[4];
#pragma unroll
        for (int fi = 0; fi < 4; ++fi)
            af[fi] = *(const short8*)(As + (wm * 64 + fi * 16 + m16) * 32 + kq);
#pragma unroll
        for (int fj = 0; fj < 4; ++fj)
            bfr[fj] = *(const short8*)(Bs + (wn * 64 + fj * 16 + m16) * 32 + kq);
#pragma unroll
        for (int fi = 0; fi < 4; ++fi)
#pragma unroll
            for (int fj = 0; fj < 4; ++fj)
                acc[fi][fj] = __builtin_amdgcn_mfma_f32_16x16x32_bf16(
                    af[fi], bfr[fj], acc[fi][fj], 0, 0, 0);
        __syncthreads();
    }
    float alpha = (mode == 2) ? alphap[aidx] : 0.f;
    int rbase = i0 + wm * 64 + (lane >> 4) * 4;
    int cbase = j0 + wn * 64 + m16;
    float s1[4] = {0.f, 0.f, 0.f, 0.f}, s2[4] = {0.f, 0.f, 0.f, 0.f};
#pragma unroll
    for (int fi = 0; fi < 4; ++fi) {
#pragma unroll
        for (int fj = 0; fj < 4; ++fj) {
            int c = cbase + fj * 16;
            float a = aux[c];
#pragma unroll
            for (int r = 0; r < 4; ++r) {
                int gr = rbase + fi * 16 + r;
                size_t oidx = (size_t)gr * ldOut + c;
                float val;
                if (mode == 2) val = resid[oidx] + alpha * (acc[fi][fj][r] + a);
                else           val = acc[fi][fj][r] + a;
                out[oidx] = val;
                s1[fj] += val; s2[fj] += val * val;
            }
        }
    }
    if (stats) {
#pragma unroll
        for (int fj = 0; fj < 4; ++fj) {
            float a1 = s1[fj], a2 = s2[fj];
            a1 += __shfl_xor(a1, 16); a1 += __shfl_xor(a1, 32);
            a2 += __shfl_xor(a2, 16); a2 += __shfl_xor(a2, 32);
            if ((lane >> 4) == 0) {
                cs1[wave][fj * 16 + m16] = a1;
                cs2[wave][fj * 16 + m16] = a2;
            }
        }
        __syncthreads();
        if (tid < 128) {
            int wnl = tid >> 6, cl = tid & 63;
            float t1 = cs1[2 * wnl][cl] + cs1[2 * wnl + 1][cl];
            float t2 = cs2[2 * wnl][cl] + cs2[2 * wnl + 1][cl];
            int c = j0 + tid;
            atomicAdd(&stats[c], (double)t1);
            atomicAdd(&stats[H_ + c], (double)t2);
        }
    }
}

// ---- gram tile body (device fn shared by gram_sym / gram_uv) ----
// D[i][j] = sq[j] - 2 <x_i, x_j>; writes both orientations when offd.
// D stores are CACHEABLE (not NT): D (134 MB) + Ap + uv fit the 256 MB LLC,
// so the topk re-read one kernel later hits LLC instead of HBM.
static __device__ __forceinline__ void gram_body(
    ushort_t* As, ushort_t* Bs, float* sg,
    const ushort_t* __restrict__ Pz, const float* __restrict__ sqz,
    float* __restrict__ Dz, int bi, int bj) {
    int i0 = bi * 128, j0 = bj * 128;
    int tid = threadIdx.x;
    int lane = tid & 63, wave = tid >> 6;
    int wm = wave & 1, wn = wave >> 1;
    int m16 = lane & 15, q4 = lane >> 4;
    int kq = q4 * 8;

    f32x4 acc[4][4];
    f32x4 zero = {0.f, 0.f, 0.f, 0.f};
#pragma unroll
    for (int i = 0; i < 4; ++i)
#pragma unroll
        for (int j = 0; j < 4; ++j) acc[i][j] = zero;

    int srow = tid >> 2;
    int skc  = (tid & 3) * 8;

    for (int k0 = 0; k0 < KP_; k0 += 32) {
        int ka = kmapA(k0), kb = kmapB(k0);
#pragma unroll
        for (int s = 0; s < 2; ++s) {
            int row = srow + s * 64;
            const ushort_t* gpA = Pz + (size_t)(i0 + row) * KPC_ + ka + skc;
            const ushort_t* gpB = Pz + (size_t)(j0 + row) * KPC_ + kb + skc;
            __builtin_amdgcn_global_load_lds(
                (const __attribute__((address_space(1))) void*)gpA,
                (__attribute__((address_space(3))) void*)(As + (size_t)(wave * 64 + s * 256) * 8),
                16, 0, 0);
            __builtin_amdgcn_global_load_lds(
                (const __attribute__((address_space(1))) void*)gpB,
                (__attribute__((address_space(3))) void*)(Bs + (size_t)(wave * 64 + s * 256) * 8),
                16, 0, 0);
        }
        __syncthreads();
        short8 af[4], bfr[4];
#pragma unroll
        for (int fi = 0; fi < 4; ++fi)
            af[fi] = *(const short8*)(As + (wm * 64 + fi * 16 + m16) * 32 + kq);
#pragma unroll
        for (int fj = 0; fj < 4; ++fj)
            bfr[fj] = *(const short8*)(Bs + (wn * 64 + fj * 16 + m16) * 32 + kq);
#pragma unroll
        for (int fi = 0; fi < 4; ++fi)
#pragma unroll
            for (int fj = 0; fj < 4; ++fj)
                acc[fi][fj] = __builtin_amdgcn_mfma_f32_16x16x32_bf16(
                    af[fi], bfr[fj], acc[fi][fj], 0, 0, 0);
        __syncthreads();
    }

    float scl[4];
#pragma unroll
    for (int fj = 0; fj < 4; ++fj) scl[fj] = sqz[j0 + wn * 64 + fj * 16 + m16];
    float sr[4][4];
#pragma unroll
    for (int fi = 0; fi < 4; ++fi) {
        float4 s4 = *(const float4*)(sqz + i0 + wm * 64 + fi * 16 + q4 * 4);
        sr[fi][0] = s4.x; sr[fi][1] = s4.y; sr[fi][2] = s4.z; sr[fi][3] = s4.w;
    }

    // normal orientation: per fi, wave-private [16][68] transpose -> f32x4 stores
    int rr = lane >> 2, cc = lane & 3;
#pragma unroll
    for (int fi = 0; fi < 4; ++fi) {
#pragma unroll
        for (int fj = 0; fj < 4; ++fj)
#pragma unroll
            for (int r = 0; r < 4; ++r)
                sg[(q4 * 4 + r) * 68 + fj * 16 + m16] = scl[fj] - 2.f * acc[fi][fj][r];
        float* drow = Dz + (size_t)(i0 + wm * 64 + fi * 16 + rr) * N_ + j0 + wn * 64;
#pragma unroll
        for (int t = 0; t < 4; ++t) {
            int chunk = cc + 4 * t;
            f32x4 o = *(const f32x4*)(sg + rr * 68 + chunk * 4);
            *(f32x4*)(drow + chunk * 4) = o;
        }
    }

    // transposed orientation (off-diag): per fi, wave-private [64][20] -> f32x4 stores
    if (bi != bj) {
#pragma unroll
        for (int fi = 0; fi < 4; ++fi) {
#pragma unroll
            for (int fj = 0; fj < 4; ++fj)
#pragma unroll
                for (int r = 0; r < 4; ++r)
                    sg[(fj * 16 + m16) * 20 + q4 * 4 + r] =
                        sr[fi][r] - 2.f * acc[fi][fj][r];
            int chunk = lane & 3;
#pragma unroll
            for (int u = 0; u < 4; ++u) {
                int cr = (lane >> 2) + 16 * u;
                f32x4 o = *(const f32x4*)(sg + cr * 20 + chunk * 4);
                *(f32x4*)(Dz + (size_t)(j0 + wn * 64 + cr) * N_ +
                          i0 + wm * 64 + fi * 16 + chunk * 4) = o;
            }
        }
    }
}

// pair decode, LPT-ordered: p<120 -> off-diag pair #p (bi<bj), else diag p-120.
static __device__ __forceinline__ void pair_decode(int p, int* pbi, int* pbj) {
    if (p < 120) {
        int bi = 0, rem = p;
        while (rem >= 15 - bi) { rem -= 15 - bi; ++bi; }
        *pbi = bi; *pbj = bi + 1 + rem;
    } else {
        *pbi = *pbj = p - 120;
    }
}

// uv gemm body (mode 0, no stats, N=512, nx=4 XCD mapping), for fusion
static __device__ __forceinline__ void uvgemm_body(
    ushort_t* As, ushort_t* Bs,
    const ushort_t* __restrict__ P, const ushort_t* __restrict__ Q,
    const float* __restrict__ aux, float* __restrict__ out, int ublk) {
    int z = ublk & 7;
    int rest = ublk >> 3;
    int xb = rest & 3;
    int ys = rest >> 2;
    int i0 = (z * 16 + ys) * 128;
    int j0 = xb * 128;
    int tid = threadIdx.x;
    int lane = tid & 63, wave = tid >> 6;
    int wm = wave & 1, wn = wave >> 1;
    int m16 = lane & 15, kq = (lane >> 4) * 8;

    f32x4 acc[4][4];
    f32x4 zero = {0.f, 0.f, 0.f, 0.f};
#pragma unroll
    for (int i = 0; i < 4; ++i)
#pragma unroll
        for (int j = 0; j < 4; ++j) acc[i][j] = zero;

    int srow = tid >> 2;
    int skc  = (tid & 3) * 8;

    for (int k0 = 0; k0 < KP_; k0 += 32) {
        int ka = kmapA(k0), kb = kmapB(k0);
#pragma unroll
        for (int s = 0; s < 2; ++s) {
            int row = srow + s * 64;
            const ushort_t* gpA = P + (size_t)(i0 + row) * KPC_ + ka + skc;
            const ushort_t* gpB = Q + (size_t)(j0 + row) * KPC_ + kb + skc;
            __builtin_amdgcn_global_load_lds(
                (const __attribute__((address_space(1))) void*)gpA,
                (__attribute__((address_space(3))) void*)(As + (size_t)(wave * 64 + s * 256) * 8),
                16, 0, 0);
            __builtin_amdgcn_global_load_lds(
                (const __attribute__((address_space(1))) void*)gpB,
                (__attribute__((address_space(3))) void*)(Bs + (size_t)(wave * 64 + s * 256) * 8),
                16, 0, 0);
        }
        __syncthreads();
        short8 af[4], bfr[4];
#pragma unroll
        for (int fi = 0; fi < 4; ++fi)
            af[fi] = *(const short8*)(As + (wm * 64 + fi * 16 + m16) * 32 + kq);
#pragma unroll
        for (int fj = 0; fj < 4; ++fj)
            bfr[fj] = *(const short8*)(Bs + (wn * 64 + fj * 16 + m16) * 32 + kq);
#pragma unroll
        for (int fi = 0; fi < 4; ++fi)
#pragma unroll
            for (int fj = 0; fj < 4; ++fj)
                acc[fi][fj] = __builtin_amdgcn_mfma_f32_16x16x32_bf16(
                    af[fi], bfr[fj], acc[fi][fj], 0, 0, 0);
        __syncthreads();
    }
    int rbase = i0 + wm * 64 + (lane >> 4) * 4;
    int cbase = j0 + wn * 64 + m16;
#pragma unroll
    for (int fi = 0; fi < 4; ++fi)
#pragma unroll
        for (int fj = 0; fj < 4; ++fj) {
            int c = cbase + fj * 16;
            float a = aux[c];
#pragma unroll
            for (int r = 0; r < 4; ++r) {
                int gr = rbase + fi * 16 + r;
                out[(size_t)gr * 512 + c] = acc[fi][fj][r] + a;
            }
        }
}

// standalone symmetric gram (small path), LPT-ordered grid 1088
__global__ __launch_bounds__(256) void gram_sym(const ushort_t* __restrict__ Ap,
                                                const float* __restrict__ sqb,
                                                float* __restrict__ D) {
    __shared__ __align__(16) ushort_t As[128 * 32];
    __shared__ __align__(16) ushort_t Bs[128 * 32];
    __shared__ __align__(16) float stg[4][1280];
    int blk = blockIdx.x;
    int z = blk & 7;
    int p = (blk < 960) ? (blk >> 3) : (120 + ((blk - 960) >> 3));
    int bi, bj;
    pair_decode(p, &bi, &bj);
    gram_body(As, Bs, stg[threadIdx.x >> 6],
              Ap + (size_t)z * N_ * KPC_, sqb + (size_t)z * N_,
              D + (size_t)z * N_ * N_, bi, bj);
}

// fused gram + uv gemm (big path): blocks [0,960) off-diag gram,
// [960,1472) uv gemm (tail-filler), [1472,1600) diag gram (cheap, last).
__global__ __launch_bounds__(256) void gram_uv(const ushort_t* __restrict__ Ap,
                                               const float* __restrict__ sqb,
                                               float* __restrict__ D,
                                               const ushort_t* __restrict__ Qcat,
                                               const float* __restrict__ bcat,
                                               float* __restrict__ uv) {
    __shared__ __align__(16) ushort_t As[128 * 32];
    __shared__ __align__(16) ushort_t Bs[128 * 32];
    __shared__ __align__(16) float stg[4][1280];
    int blk = blockIdx.x;
    if (blk >= 960 && blk < 1472) {
        uvgemm_body(As, Bs, Ap, Qcat, bcat, uv, blk - 960);
        return;
    }
    int z = blk & 7;
    int p = (blk < 960) ? (blk >> 3) : (120 + ((blk - 1472) >> 3));
    int bi, bj;
    pair_decode(p, &bi, &bj);
    gram_body(As, Bs, stg[threadIdx.x >> 6],
              Ap + (size_t)z * N_ * KPC_, sqb + (size_t)z * N_,
              D + (size_t)z * N_ * N_, bi, bj);
}

// ---- fused exact top-16 + gather (big path) ----
// One block = one 32-row strip, XCD-pinned (z = blk&7) so uv's v-half stays in
// the XCD's L2 (identical mapping to the old gather_max). Phase 1: each wave
// runs the verbatim topk16 body on 8 rows, indices -> LDS (idxb never hits
// global). Phase 2: verbatim gather body; per-thread fp32 stats partials keep
// the exact 32-row grouping/order of the old gather_max -> bitwise-identical.
// Barrier uniformity: all 4 waves run 8 iterations x 2 __syncthreads; the
// 3-tier extraction branches are wave-local (shfl only, no barriers).
__global__ __launch_bounds__(256) void knn_gather(const float* __restrict__ D,
                                                  const float* __restrict__ uv,
                                                  float* __restrict__ outp,
                                                  double* __restrict__ stats) {
    __shared__ unsigned long long cand[4][256];
    __shared__ int cnt[4];
    __shared__ int sidx[32][16];
    int blk = blockIdx.x;
    int z = blk & 7;
    int strip = blk >> 3;               // 0..63
    int r0 = z * N_ + strip * 32;
    int w = threadIdx.x >> 6, lane = threadIdx.x & 63;

    // ---- phase 1: top-16 for 8 rows per wave (verbatim topk16 body) ----
    for (int rq = 0; rq < 8; ++rq) {
        int lr = w * 8 + rq;            // 0..31 within strip
        int row = r0 + lr;
        const float* dp = D + (size_t)row * N_;
        unsigned sk[32];
#pragma unroll
        for (int t = 0; t < 8; ++t) {
            f32x4 v4 = *(const f32x4*)(dp + t * 256 + lane * 4);
#pragma unroll
            for (int j = 0; j < 4; ++j) {
                unsigned u = __float_as_uint(v4[j]);
                sk[t * 4 + j] = (u & 0x80000000u) ? ~u : (u | 0x80000000u);
            }
        }
        if (lane == 0) cnt[w] = 0;
        unsigned vm = sk[0];
#pragma unroll
        for (int i = 1; i < 32; ++i) vm = min(vm, sk[i]);
#pragma unroll
        for (int k = 2; k <= 64; k <<= 1) {
#pragma unroll
            for (int j = k >> 1; j > 0; j >>= 1) {
                unsigned pv = __shfl_xor(vm, j);
                bool up = ((lane & k) == 0);
                bool lower = ((lane & j) == 0);
                unsigned mn = min(vm, pv), mx = max(vm, pv);
                vm = (lower == up) ? mn : mx;
            }
        }
        unsigned T = __shfl(vm, 15);   // 16th smallest lane-min >= 16th order stat
        __syncthreads();
#pragma unroll
        for (int i = 0; i < 32; ++i) {
            if (sk[i] <= T) {
                unsigned col = (unsigned)((i >> 2) * 256 + lane * 4 + (i & 3));
                int s = atomicAdd(&cnt[w], 1);
                if (s < 256) cand[w][s] = ((unsigned long long)sk[i] << 32) | col;
            }
        }
        __syncthreads();
        int cn = cnt[w];
        if (cn <= 64) {
            unsigned long long mykey = (lane < cn) ? cand[w][lane] : ~0ull;
            for (int it = 0; it < 16; ++it) {
                unsigned long long best = mykey;
#pragma unroll
                for (int off = 32; off; off >>= 1) {
                    unsigned long long o = __shfl_xor(best, off);
                    if (o < best) best = o;
                }
                if (mykey == best) mykey = ~0ull;
                if (lane == 0) sidx[lr][it] = (int)(unsigned)(best & 0xffffffffu);
            }
        } else if (cn <= 256) {
            for (int it = 0; it < 16; ++it) {
                unsigned long long best = ~0ull;
                for (int i = lane; i < cn; i += 64) {
                    unsigned long long c = cand[w][i];
                    if (c < best) best = c;
                }
#pragma unroll
                for (int off = 32; off; off >>= 1) {
                    unsigned long long o = __shfl_xor(best, off);
                    if (o < best) best = o;
                }
                for (int i = lane; i < cn; i += 64)
                    if (cand[w][i] == best) cand[w][i] = ~0ull;
                if (lane == 0) sidx[lr][it] = (int)(unsigned)(best & 0xffffffffu);
            }
        } else {
            unsigned mask = 0;
            for (int it = 0; it < 16; ++it) {
                unsigned long long key = ~0ull;
#pragma unroll
                for (int i = 0; i < 32; ++i) {
                    if (!((mask >> i) & 1u)) {
                        unsigned long long k2 = ((unsigned long long)sk[i] << 32) |
                            (unsigned)((i >> 2) * 256 + lane * 4 + (i & 3));
                        if (k2 < key) key = k2;
                    }
                }
#pragma unroll
                for (int off = 32; off; off >>= 1) {
                    unsigned long long o = __shfl_xor(key, off);
                    if (o < key) key = o;
                }
                unsigned jc = (unsigned)(key & 0xffffffffu);
                int li = ((jc & 255) >> 2);
                int ii = ((jc >> 8) << 2) | (jc & 3);
                if (lane == li) mask |= 1u << ii;
                if (lane == 0) sidx[lr][it] = (int)jc;
            }
        }
    }
    __syncthreads();

    // ---- phase 2: gather (verbatim gather_max body; indices from LDS) ----
    int f = threadIdx.x;
    float s1 = 0.f, s2 = 0.f;
    for (int rr = 0; rr < 32; ++rr) {
        int row = r0 + rr;
        float m = -FLT_MAX;
#pragma unroll
        for (int k = 0; k < 16; ++k) {
            int j = sidx[rr][k];
            m = fmaxf(m, uv[((size_t)((z << 11) + j)) * 512 + 256 + f]);
        }
        float v = uv[(size_t)row * 512 + f] + m;
        outp[(size_t)row * H_ + f] = v;
        s1 += v; s2 += v * v;
    }
    atomicAdd(&stats[f], (double)s1);
    atomicAdd(&stats[H_ + f], (double)s2);
}

// ---- threshold top-16 smallest per row (small path; exact, lex tie-break) ----
__global__ __launch_bounds__(256) void topk16(const float* __restrict__ D,
                                              int* __restrict__ idxb) {
    __shared__ unsigned long long cand[4][256];
    __shared__ int cnt[4];
    int w = threadIdx.x >> 6, lane = threadIdx.x & 63;
    int row = blockIdx.x * 4 + w;
    const float* dp = D + (size_t)row * N_;
    unsigned sk[32];
#pragma unroll
    for (int t = 0; t < 8; ++t) {
        f32x4 v4 = *(const f32x4*)(dp + t * 256 + lane * 4);
#pragma unroll
        for (int j = 0; j < 4; ++j) {
            unsigned u = __float_as_uint(v4[j]);
            sk[t * 4 + j] = (u & 0x80000000u) ? ~u : (u | 0x80000000u);
        }
    }
    if (lane == 0) cnt[w] = 0;
    unsigned vm = sk[0];
#pragma unroll
    for (int i = 1; i < 32; ++i) vm = min(vm, sk[i]);
#pragma unroll
    for (int k = 2; k <= 64; k <<= 1) {
#pragma unroll
        for (int j = k >> 1; j > 0; j >>= 1) {
            unsigned pv = __shfl_xor(vm, j);
            bool up = ((lane & k) == 0);
            bool lower = ((lane & j) == 0);
            unsigned mn = min(vm, pv), mx = max(vm, pv);
            vm = (lower == up) ? mn : mx;
        }
    }
    unsigned T = __shfl(vm, 15);
    __syncthreads();
#pragma unroll
    for (int i = 0; i < 32; ++i) {
        if (sk[i] <= T) {
            unsigned col = (unsigned)((i >> 2) * 256 + lane * 4 + (i & 3));
            int s = atomicAdd(&cnt[w], 1);
            if (s < 256) cand[w][s] = ((unsigned long long)sk[i] << 32) | col;
        }
    }
    __syncthreads();
    int cn = cnt[w];
    if (cn <= 64) {
        unsigned long long mykey = (lane < cn) ? cand[w][lane] : ~0ull;
        for (int it = 0; it < 16; ++it) {
            unsigned long long best = mykey;
#pragma unroll
            for (int off = 32; off; off >>= 1) {
                unsigned long long o = __shfl_xor(best, off);
                if (o < best) best = o;
            }
            if (mykey == best) mykey = ~0ull;
            if (lane == 0) idxb[row * 16 + it] = (int)(unsigned)(best & 0xffffffffu);
        }
    } else if (cn <= 256) {
        for (int it = 0; it < 16; ++it) {
            unsigned long long best = ~0ull;
            for (int i = lane; i < cn; i += 64) {
                unsigned long long c = cand[w][i];
                if (c < best) best = c;
            }
#pragma unroll
            for (int off = 32; off; off >>= 1) {
                unsigned long long o = __shfl_xor(best, off);
                if (o < best) best = o;
            }
            for (int i = lane; i < cn; i += 64)
                if (cand[w][i] == best) cand[w][i] = ~0ull;
            if (lane == 0) idxb[row * 16 + it] = (int)(unsigned)(best & 0xffffffffu);
        }
    } else {
        unsigned mask = 0;
        for (int it = 0; it < 16; ++it) {
            unsigned long long key = ~0ull;
#pragma unroll
            for (int i = 0; i < 32; ++i) {
                if (!((mask >> i) & 1u)) {
                    unsigned long long k2 = ((unsigned long long)sk[i] << 32) |
                        (unsigned)((i >> 2) * 256 + lane * 4 + (i & 3));
                    if (k2 < key) key = k2;
                }
            }
#pragma unroll
            for (int off = 32; off; off >>= 1) {
                unsigned long long o = __shfl_xor(key, off);
                if (o < key) key = o;
            }
            unsigned jc = (unsigned)(key & 0xffffffffu);
            int li = ((jc & 255) >> 2);
            int ii = ((jc >> 8) << 2) | (jc & 3);
            if (lane == li) mask |= 1u << ii;
            if (lane == 0) idxb[row * 16 + it] = (int)jc;
        }
    }
}

// small-path gather: t[b,i,h] = uv[row][h] + max_k uv[(b,idx_k)][256+h] (+stats)
__global__ void gather_max(const float* __restrict__ uv, const int* __restrict__ idxb,
                           float* __restrict__ outp, double* __restrict__ stats) {
    int blk = blockIdx.x;
    int b = blk & 7;
    int strip = blk >> 3;               // 0..63
    int r0 = b * N_ + strip * 32;
    int f = threadIdx.x;
    float s1 = 0.f, s2 = 0.f;
    for (int rr = 0; rr < 32; ++rr) {
        int row = r0 + rr;
        const int* ip = idxb + row * 16;
        float m = -FLT_MAX;
#pragma unroll
        for (int k = 0; k < 16; ++k) {
            int j = ip[k];
            m = fmaxf(m, uv[((size_t)((b << 11) + j)) * 512 + 256 + f]);
        }
        float v = uv[(size_t)row * 512 + f] + m;
        outp[(size_t)row * H_ + f] = v;
        s1 += v; s2 += v * v;
    }
    atomicAdd(&stats[f], (double)s1);
    atomicAdd(&stats[H_ + f], (double)s2);
}

// BN+ReLU fused with compact split-bf16 packing and optional row sqnorm reduce.
// scale/shift computed in-block from the stats slot (bitwise-identical).
__global__ void bn_apply_pack(const float* __restrict__ X, const double* __restrict__ sums,
                              const float* __restrict__ g, const float* __restrict__ b,
                              ushort_t* __restrict__ Ap, float* __restrict__ sq) {
    __shared__ float scsh[512];
    int tid = threadIdx.x;
    {
        double m  = sums[tid] / (double)BN_;
        double var = sums[H_ + tid] / (double)BN_ - m * m;
        double inv = 1.0 / sqrt(var + 1e-5);
        float sc = g[tid] * (float)inv;
        scsh[tid] = sc;
        scsh[H_ + tid] = b[tid] - (float)m * sc;
    }
    __syncthreads();
    int row = blockIdx.x * 8 + (tid >> 5);
    int f0  = (tid & 31) * 8;
    const float* xp = X + (size_t)row * H_ + f0;
    f32x4 x0 = *(const f32x4*)(xp);
    f32x4 x1 = *(const f32x4*)(xp + 4);
    f32x4 sc0 = *(const f32x4*)(scsh + f0);
    f32x4 sc1 = *(const f32x4*)(scsh + f0 + 4);
    f32x4 sh0 = *(const f32x4*)(scsh + H_ + f0);
    f32x4 sh1 = *(const f32x4*)(scsh + H_ + f0 + 4);
    float v[8];
#pragma unroll
    for (int i = 0; i < 4; ++i) {
        v[i]     = fmaxf(x0[i] * sc0[i] + sh0[i], 0.f);
        v[i + 4] = fmaxf(x1[i] * sc1[i] + sh1[i], 0.f);
    }
    short8 hi8, lo8;
#pragma unroll
    for (int i = 0; i < 8; ++i) {
        ushort_t hi = f2bf(v[i]);
        ushort_t lo = f2bf(v[i] - bf2f(hi));
        hi8[i] = (short)hi; lo8[i] = (short)lo;
    }
    ushort_t* ap = Ap + (size_t)row * KPC_ + f0;
    *(short8*)(ap)      = hi8;
    *(short8*)(ap + H_) = lo8;
    if (sq) {
        float s = 0.f;
#pragma unroll
        for (int i = 0; i < 8; ++i) s += v[i] * v[i];
#pragma unroll
        for (int off = 16; off; off >>= 1) s += __shfl_down(s, off, 32);
        if ((tid & 31) == 0) sq[row] = s;
    }
}

// head gemm (N=512) with fused n-chunk maxpool: never materializes y.
__global__ __launch_bounds__(256) void head_gemm_pool(
    const ushort_t* __restrict__ P, const ushort_t* __restrict__ Q,
    const float* __restrict__ aux, float* __restrict__ pmax) {
    __shared__ __align__(16) ushort_t As[128 * 32];
    __shared__ __align__(16) ushort_t Bs[128 * 32];
    __shared__ float smax[2][2][64];
    int blk = blockIdx.x;
    int z = blk & 7;
    int rest = blk >> 3;
    int xb = rest & 3;
    int ys = rest >> 2;
    int i0 = (z * 16 + ys) * 128;
    int j0 = xb * 128;
    int tid = threadIdx.x;
    int lane = tid & 63, wave = tid >> 6;
    int wm = wave & 1, wn = wave >> 1;
    int m16 = lane & 15, kq = (lane >> 4) * 8;

    f32x4 acc[4][4];
    f32x4 zero = {0.f, 0.f, 0.f, 0.f};
#pragma unroll
    for (int i = 0; i < 4; ++i)
#pragma unroll
        for (int j = 0; j < 4; ++j) acc[i][j] = zero;

    int srow = tid >> 2;
    int skc  = (tid & 3) * 8;

    for (int k0 = 0; k0 < KP_; k0 += 32) {
        int ka = kmapA(k0), kb = kmapB(k0);
#pragma unroll
        for (int s = 0; s < 2; ++s) {
            int row = srow + s * 64;
            const ushort_t* gpA = P + (size_t)(i0 + row) * KPC_ + ka + skc;
            const ushort_t* gpB = Q + (size_t)(j0 + row) * KPC_ + kb + skc;
            __builtin_amdgcn_global_load_lds(
                (const __attribute__((address_space(1))) void*)gpA,
                (__attribute__((address_space(3))) void*)(As + (size_t)(wave * 64 + s * 256) * 8),
                16, 0, 0);
            __builtin_amdgcn_global_load_lds(
                (const __attribute__((address_space(1))) void*)gpB,
                (__attribute__((address_space(3))) void*)(Bs + (size_t)(wave * 64 + s * 256) * 8),
                16, 0, 0);
        }
        __syncthreads();
        short8 af[4], bfr[4];
#pragma unroll
        for (int fi = 0; fi < 4; ++fi)
            af[fi] = *(const short8*)(As + (wm * 64 + fi * 16 + m16) * 32 + kq);
#pragma unroll
        for (int fj = 0; fj < 4; ++fj)
            bfr[fj] = *(const short8*)(Bs + (wn * 64 + fj * 16 + m16) * 32 + kq);
#pragma unroll
        for (int fi = 0; fi < 4; ++fi)
#pragma unroll
            for (int fj = 0; fj < 4; ++fj)
                acc[fi][fj] = __builtin_amdgcn_mfma_f32_16x16x32_bf16(
                    af[fi], bfr[fj], acc[fi][fj], 0, 0, 0);
        __syncthreads();
    }
    float vmax[4];
#pragma unroll
    for (int fj = 0; fj < 4; ++fj) {
        int c = j0 + wn * 64 + m16 + fj * 16;
        float a = aux[c];
        float m = -FLT_MAX;
#pragma unroll
        for (int fi = 0; fi < 4; ++fi)
#pragma unroll
            for (int r = 0; r < 4; ++r)
                m = fmaxf(m, acc[fi][fj][r] + a);
        m = fmaxf(m, __shfl_xor(m, 16));
        m = fmaxf(m, __shfl_xor(m, 32));
        vmax[fj] = m;
    }
    if (lane < 16) {
#pragma unroll
        for (int fj = 0; fj < 4; ++fj)
            smax[wm][wn][fj * 16 + m16] = vmax[fj];
    }
    __syncthreads();
    if (tid < 128) {
        int wn2 = tid >> 6, off = tid & 63;
        float m = fmaxf(smax[0][wn2][off], smax[1][wn2][off]);
        pmax[((size_t)(z * 16 + ys)) * G_ + j0 + wn2 * 64 + off] = m;
    }
}

// fused head: 16-chunk maxpool + 3-layer MLP (replicates the proven 4-way
// K-split and red[0..3]+bias summation order -> bitwise-identical).
__global__ __launch_bounds__(256) void head3(const float* __restrict__ pmax,
    const float* __restrict__ Wm1, const float* __restrict__ bm1,
    const float* __restrict__ Wm2, const float* __restrict__ bm2,
    const float* __restrict__ Wm3, const float* __restrict__ bm3,
    float* __restrict__ out) {
    __shared__ float s0[512];
    __shared__ float s1[256];
    __shared__ float red[4][64];
    int b = blockIdx.x, tid = threadIdx.x;
    {
        float m0 = -FLT_MAX, m1 = -FLT_MAX;
        for (int c2 = 0; c2 < 16; ++c2) {
            m0 = fmaxf(m0, pmax[((size_t)(b * 16 + c2)) * G_ + tid]);
            m1 = fmaxf(m1, pmax[((size_t)(b * 16 + c2)) * G_ + 256 + tid]);
        }
        s0[tid] = m0; s0[256 + tid] = m1;
    }
    int cl = tid & 63, ks = tid >> 6;
    __syncthreads();
    // stage 1: 256 outs, K=512 (kper=128)
    for (int cg = 0; cg < 4; ++cg) {
        int c = cg * 64 + cl;
        const float* Apt = s0 + ks * 128;
        const float* Wp  = Wm1 + (size_t)(ks * 128) * M0_ + c;
        float acc = 0.f;
        for (int k = 0; k < 128; k += 8)
#pragma unroll
            for (int u2 = 0; u2 < 8; ++u2)
                acc += Apt[k + u2] * Wp[(size_t)(k + u2) * M0_];
        red[ks][cl] = acc;
        __syncthreads();
        if (ks == 0) {
            float s = red[0][cl] + red[1][cl] + red[2][cl] + red[3][cl] + bm1[c];
            s1[c] = fmaxf(s, 0.f);
        }
        __syncthreads();
    }
    // stage 2: 128 outs, K=256 (kper=64)
    float s2v[2];
    for (int cg = 0; cg < 2; ++cg) {
        int c = cg * 64 + cl;
        const float* Apt = s1 + ks * 64;
        const float* Wp  = Wm2 + (size_t)(ks * 64) * M1_ + c;
        float acc = 0.f;
        for (int k = 0; k < 64; k += 8)
#pragma unroll
            for (int u2 = 0; u2 < 8; ++u2)
                acc += Apt[k + u2] * Wp[(size_t)(k + u2) * M1_];
        red[ks][cl] = acc;
        __syncthreads();
        s2v[cg] = 0.f;
        if (ks == 0) {
            float s = red[0][cl] + red[1][cl] + red[2][cl] + red[3][cl] + bm2[c];
            s2v[cg] = fmaxf(s, 0.f);
        }
        __syncthreads();
    }
    if (ks == 0) { s0[cl] = s2v[0]; s0[64 + cl] = s2v[1]; }
    __syncthreads();
    // stage 3: 128 outs, K=128 (kper=32)
    for (int cg = 0; cg < 2; ++cg) {
        int c = cg * 64 + cl;
        const float* Apt = s0 + ks * 32;
        const float* Wp  = Wm3 + (size_t)(ks * 32) * C_ + c;
        float acc = 0.f;
        for (int k = 0; k < 32; k += 8)
#pragma unroll
            for (int u2 = 0; u2 < 8; ++u2)
                acc += Apt[k + u2] * Wp[(size_t)(k + u2) * C_];
        red[ks][cl] = acc;
        __syncthreads();
        if (ks == 0)
            out[(size_t)b * C_ + c] =
                red[0][cl] + red[1][cl] + red[2][cl] + red[3][cl] + bm3[c];
        __syncthreads();
    }
}

// ---------------- launch ----------------
extern "C" void kernel_launch(void* const* d_in, const int* in_sizes, int n_in,
                              void* d_out, int out_size, void* d_ws, size_t ws_size,
                              hipStream_t stream) {
    (void)in_sizes; (void)n_in; (void)out_size;
    if (ws_size < WS_SMALL) return;
    const bool big = (ws_size >= WS_BIG);

    const float* x    = (const float*)d_in[0];
    const float* Wf   = (const float*)d_in[2];
    const float* bfv  = (const float*)d_in[3];
    const float* Wnn  = (const float*)d_in[4];
    const float* bnn  = (const float*)d_in[5];
    const float* g1   = (const float*)d_in[6];
    const float* b1   = (const float*)d_in[7];
    const float* We   = (const float*)d_in[8];
    const float* be   = (const float*)d_in[9];
    const float* g2   = (const float*)d_in[10];
    const float* b2   = (const float*)d_in[11];
    const float* Wl   = (const float*)d_in[12];
    const float* bl   = (const float*)d_in[13];
    const float* alpha= (const float*)d_in[14];
    const float* gg   = (const float*)d_in[15];
    const float* bgb  = (const float*)d_in[16];
    const float* Wg   = (const float*)d_in[17];
    const float* bg2  = (const float*)d_in[18];
    const float* Wm1  = (const float*)d_in[19];
    const float* bm1  = (const float*)d_in[20];
    const float* Wm2  = (const float*)d_in[21];
    const float* bm2  = (const float*)d_in[22];
    const float* Wm3  = (const float*)d_in[23];
    const float* bm3  = (const float*)d_in[24];
    float* outp = (float*)d_out;

    char* ws = (char*)d_ws;
    float*    h    = (float*)(ws + OFF_H);
    ushort_t* Ap   = (ushort_t*)(ws + OFF_APACK);
    ushort_t* Qpk  = (ushort_t*)(ws + OFF_WPK);
    float*    bcatA= (float*)(ws + OFF_BCA);
    double*   sta  = (double*)(ws + OFF_STA);
    float*    sqb  = (float*)(ws + OFF_SQ);
    int*      idxb = (int*)  (ws + OFF_IDX);

    size_t offD = big ? OFF_DBIG : OFF_DSML;
    float*    dmat = (float*)(ws + offD);
    float*    t    = (float*)(ws + offD);                      // overlays D (dead)
    float*    uv   = big ? (float*)(ws + OFF_UVBIG)
                         : (float*)(ws + offD + (size_t)50331648);
    float*    pmax = (float*)(ws + offD + (size_t)84672512);   // overlays D (dead)

    ushort_t* Qwnn = Qpk + (size_t)WPK_WNN * KPC_;
    ushort_t* Qwg  = Qpk + (size_t)WPK_WG  * KPC_;

    // fused prep: feat+pack | weight packs | stats zero
    hipLaunchKernelGGL(prep, dim3(BN_ + 3840 + 9), dim3(256), 0, stream,
                       x, Wf, bfv, h, Ap, Wnn, Wl, Wg, We, be, Qpk, bcatA, sta);

    // t = h@Wnn+bnn via MFMA (t-stats -> slot 0), XCD-pinned
    hipLaunchKernelGGL(mfma_gemm, dim3(256), dim3(256), 0, stream,
                       Ap, Qwnn, bnn, t, H_, 0,
                       (const float*)nullptr, (const float*)nullptr, 0, sta, 2);

    for (int l = 0; l < L_; ++l) {
        const float* src1 = (l == 0) ? t : h;
        hipLaunchKernelGGL(bn_apply_pack, dim3(BN_ / 8), dim3(256), 0, stream,
                           src1, sta + (size_t)(2 * l) * 512,
                           g1 + l * H_, b1 + l * H_, Ap, sqb);
        if (big) {
            // fused: gram (off-diag first, diag last) + uv gemm tail-filler
            hipLaunchKernelGGL(gram_uv, dim3(1600), dim3(256), 0, stream,
                               Ap, sqb, dmat,
                               Qpk + (size_t)(WPK_QCAT + l * 512) * KPC_,
                               bcatA + (size_t)l * 512, uv);
            // fused top-16 + gather (t-stats -> slot 2l+1)
            hipLaunchKernelGGL(knn_gather, dim3(512), dim3(256), 0, stream,
                               dmat, uv, t, sta + (size_t)(2 * l + 1) * 512);
        } else {
            hipLaunchKernelGGL(gram_sym, dim3(1088), dim3(256), 0, stream,
                               Ap, sqb, dmat);
            hipLaunchKernelGGL(topk16, dim3(BN_ / 4), dim3(256), 0, stream, dmat, idxb);
            hipLaunchKernelGGL(mfma_gemm, dim3(512), dim3(256), 0, stream,
                               Ap, Qpk + (size_t)(WPK_QCAT + l * 512) * KPC_,
                               bcatA + (size_t)l * 512, uv, 512, 0,
                               (const float*)nullptr, (const float*)nullptr, 0,
                               (double*)nullptr, 4);
            hipLaunchKernelGGL(gather_max, dim3(512), dim3(256), 0, stream,
                               uv, idxb, t, sta + (size_t)(2 * l + 1) * 512);
        }
        hipLaunchKernelGGL(bn_apply_pack, dim3(BN_ / 8), dim3(256), 0, stream,
                           t, sta + (size_t)(2 * l + 1) * 512,
                           g2 + l * H_, b2 + l * H_, Ap, (float*)nullptr);
        hipLaunchKernelGGL(mfma_gemm, dim3(256), dim3(256), 0, stream,
                           Ap, Qpk + (size_t)(WPK_WL + l * 256) * KPC_,
                           bl + (size_t)l * H_, h, H_, 2,
                           h, alpha, l, sta + (size_t)(2 * l + 2) * 512, 2);
    }

    // head: BN from slot 8, pack, fused Wg-gemm+pool, fused pool2+MLP
    hipLaunchKernelGGL(bn_apply_pack, dim3(BN_ / 8), dim3(256), 0, stream,
                       h, sta + (size_t)8 * 512, gg, bgb, Ap, (float*)nullptr);
    hipLaunchKernelGGL(head_gemm_pool, dim3(512), dim3(256), 0, stream,
                       Ap, Qwg, bg2, pmax);
    hipLaunchKernelGGL(head3, dim3(8), dim3(256), 0, stream,
                       pmax, Wm1, bm1, Wm2, bm2, Wm3, bm3, outp);
}

// Round 8
// 933.761 us; speedup vs baseline: 1.1162x; 1.1162x over previous
//
#include <hip/hip_runtime.h>
#include <cfloat>

#define B_  8
#define N_  2048
#define H_  256
#define L_  4
#define K_  16
#define G_  512
#define M0_ 256
#define M1_ 128
#define C_  128
#define BN_ 16384   // B_*N_
#define KP_ 768     // effective split-bf16 K (3*H_)
#define KPC_ 512    // compact pack row stride [hi(0:256) | lo(256:512)]

typedef unsigned short ushort_t;
typedef __attribute__((ext_vector_type(8))) short short8;
typedef __attribute__((ext_vector_type(4))) float f32x4;

// ---------------- workspace layout (bytes) ----------------
// shared fixed region
#define OFF_H     ((size_t)0)            // 16 MB   h (fp32, persistent)
#define OFF_APACK ((size_t)16777216)     // 16.8 MB compact P-pack [hi|lo]
#define OFF_WPK   ((size_t)33554432)     // 3.93 MB all weight packs (3840 x 512 bf16)
#define OFF_BCA   ((size_t)37486592)     // 8 KB    bcat arena
#define OFF_STA   ((size_t)37494784)     // 36 KB   stats arena (9 x 512 doubles)
#define OFF_SQ    ((size_t)37531648)     // 64 KB
#define OFF_IDX   ((size_t)37597184)     // 1 MB -> ends 38,645,760
// big path: uv gets its own home (so it can be written concurrently with D)
#define OFF_UVBIG ((size_t)38645760)     // 33.5 MB -> ends 72,200,192
#define OFF_DSML  ((size_t)69206016)     // small path D (uv/t/pmax overlay inside)
#define OFF_DBIG  ((size_t)72200192)     // big path D
#define WS_SMALL  ((size_t)203423744)    // OFF_DSML + 134,217,728
#define WS_BIG    ((size_t)206417920)    // OFF_DBIG + 134,217,728

// weight-pack arena row offsets
#define WPK_WNN   0
#define WPK_WL    256      // + l*256
#define WPK_WG    1280
#define WPK_QCAT  1792     // + l*512

// ---------------- helpers ----------------
static __device__ __forceinline__ ushort_t f2bf(float f) {
    unsigned u = __float_as_uint(f);
    unsigned r = (u + 0x7fffu + ((u >> 16) & 1u)) >> 16;   // RNE
    return (ushort_t)r;
}
static __device__ __forceinline__ float bf2f(ushort_t h) {
    return __uint_as_float(((unsigned)h) << 16);
}
// segment remaps on the compact [hi|lo] pack.
// A-side effective order [hi,lo,hi]; B-side effective order [hi,hi,lo].
static __device__ __forceinline__ int kmapA(int k0) { return (k0 < KPC_) ? k0 : k0 - KPC_; }
static __device__ __forceinline__ int kmapB(int k0) { return (k0 < 256)  ? k0 : k0 - 256; }

// ---------------- fused prep: feat_pack + pack_all + stats zero ----------------
__global__ void prep(const float* __restrict__ x, const float* __restrict__ Wf,
                     const float* __restrict__ bfv, float* __restrict__ h,
                     ushort_t* __restrict__ Ap,
                     const float* __restrict__ Wnn, const float* __restrict__ Wl,
                     const float* __restrict__ Wg, const float* __restrict__ We,
                     const float* __restrict__ be, ushort_t* __restrict__ Qp,
                     float* __restrict__ bcat, double* __restrict__ sta) {
    int blk = blockIdx.x;
    int tid = threadIdx.x;
    if (blk < BN_) {
        int pt = blk, f = tid;
        float x0 = x[pt * 3 + 0], x1 = x[pt * 3 + 1], x2 = x[pt * 3 + 2];
        float v = x0 * Wf[f] + x1 * Wf[H_ + f] + x2 * Wf[2 * H_ + f] + bfv[f];
        h[(size_t)pt * H_ + f] = v;
        ushort_t hi = f2bf(v), lo = f2bf(v - bf2f(hi));
        size_t base = (size_t)pt * KPC_;
        Ap[base + f] = hi; Ap[base + H_ + f] = lo;
    } else if (blk < BN_ + 3840) {
        int row = blk - BN_, k = tid;
        float w;
        if (row < 1792) {
            const float* W; int Nd, n;
            if (row < 256)        { W = Wnn; Nd = 256; n = row; }
            else if (row < 1280)  { int l = (row - 256) >> 8;
                                    W = Wl + (size_t)l * (H_ * H_); Nd = 256; n = (row - 256) & 255; }
            else                  { W = Wg; Nd = 512; n = row - 1280; }
            w = W[(size_t)k * Nd + n];
        } else {
            int rr = row - 1792; int l = rr >> 9; int n = rr & 511;
            const float* We_l = We + (size_t)l * 2 * H_ * H_;
            if (n < H_) w = We_l[(size_t)k * H_ + n] - We_l[(size_t)H_ * H_ + (size_t)k * H_ + n];
            else        w = We_l[(size_t)H_ * H_ + (size_t)k * H_ + (n - H_)];
            if (k == 0) bcat[l * 512 + n] = (n < H_) ? be[l * H_ + n] : 0.f;
        }
        ushort_t hi = f2bf(w), lo = f2bf(w - bf2f(hi));
        size_t base = (size_t)row * KPC_;
        Qp[base + k] = hi; Qp[base + H_ + k] = lo;
    } else {
        int slot = blk - (BN_ + 3840);
        sta[(size_t)slot * 512 + tid] = 0.0;
        sta[(size_t)slot * 512 + 256 + tid] = 0.0;
    }
}

// ---- split-bf16 MFMA GEMM core (compact packs, K=768 via remaps) ----
// mode 0: out[r][c] = acc + aux[c]
// mode 2: out[r][c] = resid[r][c] + alphap[aidx]*(acc+aux[c])
// stats != nullptr: accumulate per-column sum/sumsq of written values
// nx != 0: 1-D grid of nx*128 blocks, XCD-pinned: z=blk&7 owns batch z's rows.
__global__ __launch_bounds__(256) void mfma_gemm(
    const ushort_t* __restrict__ P, const ushort_t* __restrict__ Q,
    const float* __restrict__ aux, float* __restrict__ out,
    int ldOut, int mode, const float* __restrict__ resid,
    const float* __restrict__ alphap, int aidx, double* __restrict__ stats,
    int nx) {
    __shared__ __align__(16) ushort_t As[128 * 32];
    __shared__ __align__(16) ushort_t Bs[128 * 32];
    __shared__ float cs1[4][64], cs2[4][64];
    int i0, j0;
    if (nx) {
        int blk = blockIdx.x;
        int z = blk & 7;
        int rest = blk >> 3;
        int xb = rest % nx;
        int ys = rest / nx;            // 0..15
        i0 = (z * 16 + ys) * 128;
        j0 = xb * 128;
    } else {
        i0 = blockIdx.y * 128; j0 = blockIdx.x * 128;
    }
    int tid = threadIdx.x;
    int lane = tid & 63, wave = tid >> 6;
    int wm = wave & 1, wn = wave >> 1;
    int m16 = lane & 15, kq = (lane >> 4) * 8;

    f32x4 acc[4][4];
    f32x4 zero = {0.f, 0.f, 0.f, 0.f};
#pragma unroll
    for (int i = 0; i < 4; ++i)
#pragma unroll
        for (int j = 0; j < 4; ++j) acc[i][j] = zero;

    int srow = tid >> 2;
    int skc  = (tid & 3) * 8;

    for (int k0 = 0; k0 < KP_; k0 += 32) {
        int ka = kmapA(k0), kb = kmapB(k0);
#pragma unroll
        for (int s = 0; s < 2; ++s) {
            int row = srow + s * 64;
            const ushort_t* gpA = P + (size_t)(i0 + row) * KPC_ + ka + skc;
            const ushort_t* gpB = Q + (size_t)(j0 + row) * KPC_ + kb + skc;
            __builtin_amdgcn_global_load_lds(
                (const __attribute__((address_space(1))) void*)gpA,
                (__attribute__((address_space(3))) void*)(As + (size_t)(wave * 64 + s * 256) * 8),
                16, 0, 0);
            __builtin_amdgcn_global_load_lds(
                (const __attribute__((address_space(1))) void*)gpB,
                (__attribute__((address_space(3))) void*)(Bs + (size_t)(wave * 64 + s * 256) * 8),
                16, 0, 0);
        }
        __syncthreads();
        short8 af[4], bfr[4];
#pragma unroll
        for (int fi = 0; fi < 4; ++fi)
            af[fi] = *(const short8*)(As + (wm * 64 + fi * 16 + m16) * 32 + kq);
#pragma unroll
        for (int fj = 0; fj < 4; ++fj)
            bfr[fj] = *(const short8*)(Bs + (wn * 64 + fj * 16 + m16) * 32 + kq);
#pragma unroll
        for (int fi = 0; fi < 4; ++fi)
#pragma unroll
            for (int fj = 0; fj < 4; ++fj)
                acc[fi][fj] = __builtin_amdgcn_mfma_f32_16x16x32_bf16(
                    af[fi], bfr[fj], acc[fi][fj], 0, 0, 0);
        __syncthreads();
    }
    float alpha = (mode == 2) ? alphap[aidx] : 0.f;
    int rbase = i0 + wm * 64 + (lane >> 4) * 4;
    int cbase = j0 + wn * 64 + m16;
    float s1[4] = {0.f, 0.f, 0.f, 0.f}, s2[4] = {0.f, 0.f, 0.f, 0.f};
#pragma unroll
    for (int fi = 0; fi < 4; ++fi) {
#pragma unroll
        for (int fj = 0; fj < 4; ++fj) {
            int c = cbase + fj * 16;
            float a = aux[c];
#pragma unroll
            for (int r = 0; r < 4; ++r) {
                int gr = rbase + fi * 16 + r;
                size_t oidx = (size_t)gr * ldOut + c;
                float val;
                if (mode == 2) val = resid[oidx] + alpha * (acc[fi][fj][r] + a);
                else           val = acc[fi][fj][r] + a;
                out[oidx] = val;
                s1[fj] += val; s2[fj] += val * val;
            }
        }
    }
    if (stats) {
#pragma unroll
        for (int fj = 0; fj < 4; ++fj) {
            float a1 = s1[fj], a2 = s2[fj];
            a1 += __shfl_xor(a1, 16); a1 += __shfl_xor(a1, 32);
            a2 += __shfl_xor(a2, 16); a2 += __shfl_xor(a2, 32);
            if ((lane >> 4) == 0) {
                cs1[wave][fj * 16 + m16] = a1;
                cs2[wave][fj * 16 + m16] = a2;
            }
        }
        __syncthreads();
        if (tid < 128) {
            int wnl = tid >> 6, cl = tid & 63;
            float t1 = cs1[2 * wnl][cl] + cs1[2 * wnl + 1][cl];
            float t2 = cs2[2 * wnl][cl] + cs2[2 * wnl + 1][cl];
            int c = j0 + tid;
            atomicAdd(&stats[c], (double)t1);
            atomicAdd(&stats[H_ + c], (double)t2);
        }
    }
}

// ---- gram tile body (BK=64, shared by gram_sym / gram_uv) ----
// D[i][j] = sq[j] - 2 <x_i, x_j>; writes both orientations when offd.
// BK=64: stage two 32-col halves per step (8 back-to-back global_load_lds ->
// 2x load MLP), then run the two MFMA sub-steps IN ORIGINAL k ORDER
// (kk=0 then kk=1, same fi/fj order) -> bitwise-identical accumulation,
// half the barriers (12 iters x 2 vs 24 x 2).
// As/Bs are [2][128][32] (16 KB each); sg (epilogue pool) ALIASES them via
// dynamic LDS (As/Bs dead after the final barrier) -> 32 KB/block, 5 blocks/CU.
static __device__ __forceinline__ void gram_body(
    ushort_t* As, ushort_t* Bs, float* sg,
    const ushort_t* __restrict__ Pz, const float* __restrict__ sqz,
    float* __restrict__ Dz, int bi, int bj) {
    int i0 = bi * 128, j0 = bj * 128;
    int tid = threadIdx.x;
    int lane = tid & 63, wave = tid >> 6;
    int wm = wave & 1, wn = wave >> 1;
    int m16 = lane & 15, q4 = lane >> 4;
    int kq = q4 * 8;

    f32x4 acc[4][4];
    f32x4 zero = {0.f, 0.f, 0.f, 0.f};
#pragma unroll
    for (int i = 0; i < 4; ++i)
#pragma unroll
        for (int j = 0; j < 4; ++j) acc[i][j] = zero;

    int srow = tid >> 2;
    int skc  = (tid & 3) * 8;

    for (int k0 = 0; k0 < KP_; k0 += 64) {
#pragma unroll
        for (int hh = 0; hh < 2; ++hh) {
            int ka = kmapA(k0 + hh * 32), kb = kmapB(k0 + hh * 32);
#pragma unroll
            for (int s = 0; s < 2; ++s) {
                int row = srow + s * 64;
                const ushort_t* gpA = Pz + (size_t)(i0 + row) * KPC_ + ka + skc;
                const ushort_t* gpB = Pz + (size_t)(j0 + row) * KPC_ + kb + skc;
                __builtin_amdgcn_global_load_lds(
                    (const __attribute__((address_space(1))) void*)gpA,
                    (__attribute__((address_space(3))) void*)(As + hh * 4096 +
                        (size_t)(wave * 64 + s * 256) * 8),
                    16, 0, 0);
                __builtin_amdgcn_global_load_lds(
                    (const __attribute__((address_space(1))) void*)gpB,
                    (__attribute__((address_space(3))) void*)(Bs + hh * 4096 +
                        (size_t)(wave * 64 + s * 256) * 8),
                    16, 0, 0);
            }
        }
        __syncthreads();
#pragma unroll
        for (int kk = 0; kk < 2; ++kk) {
            const ushort_t* Ah = As + kk * 4096;
            const ushort_t* Bh = Bs + kk * 4096;
            short8 af[4], bfr[4];
#pragma unroll
            for (int fi = 0; fi < 4; ++fi)
                af[fi] = *(const short8*)(Ah + (wm * 64 + fi * 16 + m16) * 32 + kq);
#pragma unroll
            for (int fj = 0; fj < 4; ++fj)
                bfr[fj] = *(const short8*)(Bh + (wn * 64 + fj * 16 + m16) * 32 + kq);
#pragma unroll
            for (int fi = 0; fi < 4; ++fi)
#pragma unroll
                for (int fj = 0; fj < 4; ++fj)
                    acc[fi][fj] = __builtin_amdgcn_mfma_f32_16x16x32_bf16(
                        af[fi], bfr[fj], acc[fi][fj], 0, 0, 0);
        }
        __syncthreads();
    }

    // ---- epilogue (past final barrier: As/Bs dead, sg aliases them) ----
    float scl[4];
#pragma unroll
    for (int fj = 0; fj < 4; ++fj) scl[fj] = sqz[j0 + wn * 64 + fj * 16 + m16];
    float sr[4][4];
#pragma unroll
    for (int fi = 0; fi < 4; ++fi) {
        float4 s4 = *(const float4*)(sqz + i0 + wm * 64 + fi * 16 + q4 * 4);
        sr[fi][0] = s4.x; sr[fi][1] = s4.y; sr[fi][2] = s4.z; sr[fi][3] = s4.w;
    }

    // normal orientation: per fi, wave-private [16][68] transpose -> f32x4 stores
    int rr = lane >> 2, cc = lane & 3;
#pragma unroll
    for (int fi = 0; fi < 4; ++fi) {
#pragma unroll
        for (int fj = 0; fj < 4; ++fj)
#pragma unroll
            for (int r = 0; r < 4; ++r)
                sg[(q4 * 4 + r) * 68 + fj * 16 + m16] = scl[fj] - 2.f * acc[fi][fj][r];
        float* drow = Dz + (size_t)(i0 + wm * 64 + fi * 16 + rr) * N_ + j0 + wn * 64;
#pragma unroll
        for (int t = 0; t < 4; ++t) {
            int chunk = cc + 4 * t;
            f32x4 o = *(const f32x4*)(sg + rr * 68 + chunk * 4);
            *(f32x4*)(drow + chunk * 4) = o;
        }
    }

    // transposed orientation (off-diag): per fi, wave-private [64][20] -> f32x4 stores
    if (bi != bj) {
#pragma unroll
        for (int fi = 0; fi < 4; ++fi) {
#pragma unroll
            for (int fj = 0; fj < 4; ++fj)
#pragma unroll
                for (int r = 0; r < 4; ++r)
                    sg[(fj * 16 + m16) * 20 + q4 * 4 + r] =
                        sr[fi][r] - 2.f * acc[fi][fj][r];
            int chunk = lane & 3;
#pragma unroll
            for (int u = 0; u < 4; ++u) {
                int cr = (lane >> 2) + 16 * u;
                f32x4 o = *(const f32x4*)(sg + cr * 20 + chunk * 4);
                *(f32x4*)(Dz + (size_t)(j0 + wn * 64 + cr) * N_ +
                          i0 + wm * 64 + fi * 16 + chunk * 4) = o;
            }
        }
    }
}

// pair decode, LPT-ordered: p<120 -> off-diag pair #p (bi<bj), else diag p-120.
static __device__ __forceinline__ void pair_decode(int p, int* pbi, int* pbj) {
    if (p < 120) {
        int bi = 0, rem = p;
        while (rem >= 15 - bi) { rem -= 15 - bi; ++bi; }
        *pbi = bi; *pbj = bi + 1 + rem;
    } else {
        *pbi = *pbj = p - 120;
    }
}

// uv gemm body (BK=64, mode-0, no stats, N=512, nx=4 XCD mapping), for fusion
static __device__ __forceinline__ void uvgemm_body(
    ushort_t* As, ushort_t* Bs,
    const ushort_t* __restrict__ P, const ushort_t* __restrict__ Q,
    const float* __restrict__ aux, float* __restrict__ out, int ublk) {
    int z = ublk & 7;
    int rest = ublk >> 3;
    int xb = rest & 3;
    int ys = rest >> 2;
    int i0 = (z * 16 + ys) * 128;
    int j0 = xb * 128;
    int tid = threadIdx.x;
    int lane = tid & 63, wave = tid >> 6;
    int wm = wave & 1, wn = wave >> 1;
    int m16 = lane & 15, kq = (lane >> 4) * 8;

    f32x4 acc[4][4];
    f32x4 zero = {0.f, 0.f, 0.f, 0.f};
#pragma unroll
    for (int i = 0; i < 4; ++i)
#pragma unroll
        for (int j = 0; j < 4; ++j) acc[i][j] = zero;

    int srow = tid >> 2;
    int skc  = (tid & 3) * 8;

    for (int k0 = 0; k0 < KP_; k0 += 64) {
#pragma unroll
        for (int hh = 0; hh < 2; ++hh) {
            int ka = kmapA(k0 + hh * 32), kb = kmapB(k0 + hh * 32);
#pragma unroll
            for (int s = 0; s < 2; ++s) {
                int row = srow + s * 64;
                const ushort_t* gpA = P + (size_t)(i0 + row) * KPC_ + ka + skc;
                const ushort_t* gpB = Q + (size_t)(j0 + row) * KPC_ + kb + skc;
                __builtin_amdgcn_global_load_lds(
                    (const __attribute__((address_space(1))) void*)gpA,
                    (__attribute__((address_space(3))) void*)(As + hh * 4096 +
                        (size_t)(wave * 64 + s * 256) * 8),
                    16, 0, 0);
                __builtin_amdgcn_global_load_lds(
                    (const __attribute__((address_space(1))) void*)gpB,
                    (__attribute__((address_space(3))) void*)(Bs + hh * 4096 +
                        (size_t)(wave * 64 + s * 256) * 8),
                    16, 0, 0);
            }
        }
        __syncthreads();
#pragma unroll
        for (int kk = 0; kk < 2; ++kk) {
            const ushort_t* Ah = As + kk * 4096;
            const ushort_t* Bh = Bs + kk * 4096;
            short8 af[4], bfr[4];
#pragma unroll
            for (int fi = 0; fi < 4; ++fi)
                af[fi] = *(const short8*)(Ah + (wm * 64 + fi * 16 + m16) * 32 + kq);
#pragma unroll
            for (int fj = 0; fj < 4; ++fj)
                bfr[fj] = *(const short8*)(Bh + (wn * 64 + fj * 16 + m16) * 32 + kq);
#pragma unroll
            for (int fi = 0; fi < 4; ++fi)
#pragma unroll
                for (int fj = 0; fj < 4; ++fj)
                    acc[fi][fj] = __builtin_amdgcn_mfma_f32_16x16x32_bf16(
                        af[fi], bfr[fj], acc[fi][fj], 0, 0, 0);
        }
        __syncthreads();
    }
    int rbase = i0 + wm * 64 + (lane >> 4) * 4;
    int cbase = j0 + wn * 64 + m16;
#pragma unroll
    for (int fi = 0; fi < 4; ++fi)
#pragma unroll
        for (int fj = 0; fj < 4; ++fj) {
            int c = cbase + fj * 16;
            float a = aux[c];
#pragma unroll
            for (int r = 0; r < 4; ++r) {
                int gr = rbase + fi * 16 + r;
                out[(size_t)gr * 512 + c] = acc[fi][fj][r] + a;
            }
        }
}

// dynamic-LDS size for gram kernels: max(As+Bs = 32 KB, stg = 20 KB) = 32 KB
#define GRAM_LDS 32768

// standalone symmetric gram (small path), LPT-ordered grid 1088
__global__ __launch_bounds__(256) void gram_sym(const ushort_t* __restrict__ Ap,
                                                const float* __restrict__ sqb,
                                                float* __restrict__ D) {
    extern __shared__ __align__(16) char dyns[];
    ushort_t* As = (ushort_t*)dyns;          // [2][128][32] = 16 KB
    ushort_t* Bs = As + 8192;                // 16 KB
    float* stg   = (float*)dyns;             // epilogue alias (K-loop dead)
    int blk = blockIdx.x;
    int z = blk & 7;
    int p = (blk < 960) ? (blk >> 3) : (120 + ((blk - 960) >> 3));
    int bi, bj;
    pair_decode(p, &bi, &bj);
    gram_body(As, Bs, stg + (threadIdx.x >> 6) * 1280,
              Ap + (size_t)z * N_ * KPC_, sqb + (size_t)z * N_,
              D + (size_t)z * N_ * N_, bi, bj);
}

// fused gram + uv gemm (big path): blocks [0,960) off-diag gram,
// [960,1472) uv gemm (tail-filler), [1472,1600) diag gram (cheap, last).
__global__ __launch_bounds__(256) void gram_uv(const ushort_t* __restrict__ Ap,
                                               const float* __restrict__ sqb,
                                               float* __restrict__ D,
                                               const ushort_t* __restrict__ Qcat,
                                               const float* __restrict__ bcat,
                                               float* __restrict__ uv) {
    extern __shared__ __align__(16) char dyns[];
    ushort_t* As = (ushort_t*)dyns;          // [2][128][32] = 16 KB
    ushort_t* Bs = As + 8192;                // 16 KB
    float* stg   = (float*)dyns;             // epilogue alias (K-loop dead)
    int blk = blockIdx.x;
    if (blk >= 960 && blk < 1472) {
        uvgemm_body(As, Bs, Ap, Qcat, bcat, uv, blk - 960);
        return;
    }
    int z = blk & 7;
    int p = (blk < 960) ? (blk >> 3) : (120 + ((blk - 1472) >> 3));
    int bi, bj;
    pair_decode(p, &bi, &bj);
    gram_body(As, Bs, stg + (threadIdx.x >> 6) * 1280,
              Ap + (size_t)z * N_ * KPC_, sqb + (size_t)z * N_,
              D + (size_t)z * N_ * N_, bi, bj);
}

// ---- threshold top-16 smallest per row (exact, lex (value,col) tie-break) ----
// Cacheable reads: D is mostly LLC-resident (written cacheable by gram).
__global__ __launch_bounds__(256) void topk16(const float* __restrict__ D,
                                              int* __restrict__ idxb) {
    __shared__ unsigned long long cand[4][256];
    __shared__ int cnt[4];
    int w = threadIdx.x >> 6, lane = threadIdx.x & 63;
    int row = blockIdx.x * 4 + w;
    const float* dp = D + (size_t)row * N_;
    unsigned sk[32];
#pragma unroll
    for (int t = 0; t < 8; ++t) {
        f32x4 v4 = *(const f32x4*)(dp + t * 256 + lane * 4);
#pragma unroll
        for (int j = 0; j < 4; ++j) {
            unsigned u = __float_as_uint(v4[j]);
            sk[t * 4 + j] = (u & 0x80000000u) ? ~u : (u | 0x80000000u);
        }
    }
    if (lane == 0) cnt[w] = 0;
    unsigned vm = sk[0];
#pragma unroll
    for (int i = 1; i < 32; ++i) vm = min(vm, sk[i]);
#pragma unroll
    for (int k = 2; k <= 64; k <<= 1) {
#pragma unroll
        for (int j = k >> 1; j > 0; j >>= 1) {
            unsigned pv = __shfl_xor(vm, j);
            bool up = ((lane & k) == 0);
            bool lower = ((lane & j) == 0);
            unsigned mn = min(vm, pv), mx = max(vm, pv);
            vm = (lower == up) ? mn : mx;
        }
    }
    unsigned T = __shfl(vm, 15);   // 16th smallest lane-min >= 16th order statistic
    __syncthreads();
#pragma unroll
    for (int i = 0; i < 32; ++i) {
        if (sk[i] <= T) {
            unsigned col = (unsigned)((i >> 2) * 256 + lane * 4 + (i & 3));
            int s = atomicAdd(&cnt[w], 1);
            if (s < 256) cand[w][s] = ((unsigned long long)sk[i] << 32) | col;
        }
    }
    __syncthreads();
    int cn = cnt[w];
    if (cn <= 64) {
        unsigned long long mykey = (lane < cn) ? cand[w][lane] : ~0ull;
        for (int it = 0; it < 16; ++it) {
            unsigned long long best = mykey;
#pragma unroll
            for (int off = 32; off; off >>= 1) {
                unsigned long long o = __shfl_xor(best, off);
                if (o < best) best = o;
            }
            if (mykey == best) mykey = ~0ull;
            if (lane == 0) idxb[row * 16 + it] = (int)(unsigned)(best & 0xffffffffu);
        }
    } else if (cn <= 256) {
        for (int it = 0; it < 16; ++it) {
            unsigned long long best = ~0ull;
            for (int i = lane; i < cn; i += 64) {
                unsigned long long c = cand[w][i];
                if (c < best) best = c;
            }
#pragma unroll
            for (int off = 32; off; off >>= 1) {
                unsigned long long o = __shfl_xor(best, off);
                if (o < best) best = o;
            }
            for (int i = lane; i < cn; i += 64)
                if (cand[w][i] == best) cand[w][i] = ~0ull;
            if (lane == 0) idxb[row * 16 + it] = (int)(unsigned)(best & 0xffffffffu);
        }
    } else {
        unsigned mask = 0;
        for (int it = 0; it < 16; ++it) {
            unsigned long long key = ~0ull;
#pragma unroll
            for (int i = 0; i < 32; ++i) {
                if (!((mask >> i) & 1u)) {
                    unsigned long long k2 = ((unsigned long long)sk[i] << 32) |
                        (unsigned)((i >> 2) * 256 + lane * 4 + (i & 3));
                    if (k2 < key) key = k2;
                }
            }
#pragma unroll
            for (int off = 32; off; off >>= 1) {
                unsigned long long o = __shfl_xor(key, off);
                if (o < key) key = o;
            }
            unsigned jc = (unsigned)(key & 0xffffffffu);
            int li = ((jc & 255) >> 2);
            int ii = ((jc >> 8) << 2) | (jc & 3);
            if (lane == li) mask |= 1u << ii;
            if (lane == 0) idxb[row * 16 + it] = (int)jc;
        }
    }
}

// t[b,i,h] = uv[row][h] + max_k uv[(b,idx_k)][256+h]; accumulates BN stats of t.
// XCD-pinned: z = blk&7 -> each XCD gathers within its own batch's 2 MB v-half.
__global__ void gather_max(const float* __restrict__ uv, const int* __restrict__ idxb,
                           float* __restrict__ outp, double* __restrict__ stats) {
    int blk = blockIdx.x;
    int b = blk & 7;
    int strip = blk >> 3;               // 0..63
    int r0 = b * N_ + strip * 32;
    int f = threadIdx.x;
    float s1 = 0.f, s2 = 0.f;
    for (int rr = 0; rr < 32; ++rr) {
        int row = r0 + rr;
        const int* ip = idxb + row * 16;
        float m = -FLT_MAX;
#pragma unroll
        for (int k = 0; k < 16; ++k) {
            int j = ip[k];
            m = fmaxf(m, uv[((size_t)((b << 11) + j)) * 512 + 256 + f]);
        }
        float v = uv[(size_t)row * 512 + f] + m;
        outp[(size_t)row * H_ + f] = v;
        s1 += v; s2 += v * v;
    }
    atomicAdd(&stats[f], (double)s1);
    atomicAdd(&stats[H_ + f], (double)s2);
}

// BN+ReLU fused with compact split-bf16 packing and optional row sqnorm reduce.
// scale/shift computed in-block from the stats slot (bitwise-identical).
__global__ void bn_apply_pack(const float* __restrict__ X, const double* __restrict__ sums,
                              const float* __restrict__ g, const float* __restrict__ b,
                              ushort_t* __restrict__ Ap, float* __restrict__ sq) {
    __shared__ float scsh[512];
    int tid = threadIdx.x;
    {
        double m  = sums[tid] / (double)BN_;
        double var = sums[H_ + tid] / (double)BN_ - m * m;
        double inv = 1.0 / sqrt(var + 1e-5);
        float sc = g[tid] * (float)inv;
        scsh[tid] = sc;
        scsh[H_ + tid] = b[tid] - (float)m * sc;
    }
    __syncthreads();
    int row = blockIdx.x * 8 + (tid >> 5);
    int f0  = (tid & 31) * 8;
    const float* xp = X + (size_t)row * H_ + f0;
    f32x4 x0 = *(const f32x4*)(xp);
    f32x4 x1 = *(const f32x4*)(xp + 4);
    f32x4 sc0 = *(const f32x4*)(scsh + f0);
    f32x4 sc1 = *(const f32x4*)(scsh + f0 + 4);
    f32x4 sh0 = *(const f32x4*)(scsh + H_ + f0);
    f32x4 sh1 = *(const f32x4*)(scsh + H_ + f0 + 4);
    float v[8];
#pragma unroll
    for (int i = 0; i < 4; ++i) {
        v[i]     = fmaxf(x0[i] * sc0[i] + sh0[i], 0.f);
        v[i + 4] = fmaxf(x1[i] * sc1[i] + sh1[i], 0.f);
    }
    short8 hi8, lo8;
#pragma unroll
    for (int i = 0; i < 8; ++i) {
        ushort_t hi = f2bf(v[i]);
        ushort_t lo = f2bf(v[i] - bf2f(hi));
        hi8[i] = (short)hi; lo8[i] = (short)lo;
    }
    ushort_t* ap = Ap + (size_t)row * KPC_ + f0;
    *(short8*)(ap)      = hi8;
    *(short8*)(ap + H_) = lo8;
    if (sq) {
        float s = 0.f;
#pragma unroll
        for (int i = 0; i < 8; ++i) s += v[i] * v[i];
#pragma unroll
        for (int off = 16; off; off >>= 1) s += __shfl_down(s, off, 32);
        if ((tid & 31) == 0) sq[row] = s;
    }
}

// head gemm (N=512) with fused n-chunk maxpool: never materializes y.
__global__ __launch_bounds__(256) void head_gemm_pool(
    const ushort_t* __restrict__ P, const ushort_t* __restrict__ Q,
    const float* __restrict__ aux, float* __restrict__ pmax) {
    __shared__ __align__(16) ushort_t As[128 * 32];
    __shared__ __align__(16) ushort_t Bs[128 * 32];
    __shared__ float smax[2][2][64];
    int blk = blockIdx.x;
    int z = blk & 7;
    int rest = blk >> 3;
    int xb = rest & 3;
    int ys = rest >> 2;
    int i0 = (z * 16 + ys) * 128;
    int j0 = xb * 128;
    int tid = threadIdx.x;
    int lane = tid & 63, wave = tid >> 6;
    int wm = wave & 1, wn = wave >> 1;
    int m16 = lane & 15, kq = (lane >> 4) * 8;

    f32x4 acc[4][4];
    f32x4 zero = {0.f, 0.f, 0.f, 0.f};
#pragma unroll
    for (int i = 0; i < 4; ++i)
#pragma unroll
        for (int j = 0; j < 4; ++j) acc[i][j] = zero;

    int srow = tid >> 2;
    int skc  = (tid & 3) * 8;

    for (int k0 = 0; k0 < KP_; k0 += 32) {
        int ka = kmapA(k0), kb = kmapB(k0);
#pragma unroll
        for (int s = 0; s < 2; ++s) {
            int row = srow + s * 64;
            const ushort_t* gpA = P + (size_t)(i0 + row) * KPC_ + ka + skc;
            const ushort_t* gpB = Q + (size_t)(j0 + row) * KPC_ + kb + skc;
            __builtin_amdgcn_global_load_lds(
                (const __attribute__((address_space(1))) void*)gpA,
                (__attribute__((address_space(3))) void*)(As + (size_t)(wave * 64 + s * 256) * 8),
                16, 0, 0);
            __builtin_amdgcn_global_load_lds(
                (const __attribute__((address_space(1))) void*)gpB,
                (__attribute__((address_space(3))) void*)(Bs + (size_t)(wave * 64 + s * 256) * 8),
                16, 0, 0);
        }
        __syncthreads();
        short8 af[4], bfr[4];
#pragma unroll
        for (int fi = 0; fi < 4; ++fi)
            af[fi] = *(const short8*)(As + (wm * 64 + fi * 16 + m16) * 32 + kq);
#pragma unroll
        for (int fj = 0; fj < 4; ++fj)
            bfr[fj] = *(const short8*)(Bs + (wn * 64 + fj * 16 + m16) * 32 + kq);
#pragma unroll
        for (int fi = 0; fi < 4; ++fi)
#pragma unroll
            for (int fj = 0; fj < 4; ++fj)
                acc[fi][fj] = __builtin_amdgcn_mfma_f32_16x16x32_bf16(
                    af[fi], bfr[fj], acc[fi][fj], 0, 0, 0);
        __syncthreads();
    }
    float vmax[4];
#pragma unroll
    for (int fj = 0; fj < 4; ++fj) {
        int c = j0 + wn * 64 + m16 + fj * 16;
        float a = aux[c];
        float m = -FLT_MAX;
#pragma unroll
        for (int fi = 0; fi < 4; ++fi)
#pragma unroll
            for (int r = 0; r < 4; ++r)
                m = fmaxf(m, acc[fi][fj][r] + a);
        m = fmaxf(m, __shfl_xor(m, 16));
        m = fmaxf(m, __shfl_xor(m, 32));
        vmax[fj] = m;
    }
    if (lane < 16) {
#pragma unroll
        for (int fj = 0; fj < 4; ++fj)
            smax[wm][wn][fj * 16 + m16] = vmax[fj];
    }
    __syncthreads();
    if (tid < 128) {
        int wn2 = tid >> 6, off = tid & 63;
        float m = fmaxf(smax[0][wn2][off], smax[1][wn2][off]);
        pmax[((size_t)(z * 16 + ys)) * G_ + j0 + wn2 * 64 + off] = m;
    }
}

// fused head: 16-chunk maxpool + 3-layer MLP (replicates the proven 4-way
// K-split and red[0..3]+bias summation order -> bitwise-identical).
__global__ __launch_bounds__(256) void head3(const float* __restrict__ pmax,
    const float* __restrict__ Wm1, const float* __restrict__ bm1,
    const float* __restrict__ Wm2, const float* __restrict__ bm2,
    const float* __restrict__ Wm3, const float* __restrict__ bm3,
    float* __restrict__ out) {
    __shared__ float s0[512];
    __shared__ float s1[256];
    __shared__ float red[4][64];
    int b = blockIdx.x, tid = threadIdx.x;
    {
        float m0 = -FLT_MAX, m1 = -FLT_MAX;
        for (int c2 = 0; c2 < 16; ++c2) {
            m0 = fmaxf(m0, pmax[((size_t)(b * 16 + c2)) * G_ + tid]);
            m1 = fmaxf(m1, pmax[((size_t)(b * 16 + c2)) * G_ + 256 + tid]);
        }
        s0[tid] = m0; s0[256 + tid] = m1;
    }
    int cl = tid & 63, ks = tid >> 6;
    __syncthreads();
    // stage 1: 256 outs, K=512 (kper=128)
    for (int cg = 0; cg < 4; ++cg) {
        int c = cg * 64 + cl;
        const float* Apt = s0 + ks * 128;
        const float* Wp  = Wm1 + (size_t)(ks * 128) * M0_ + c;
        float acc = 0.f;
        for (int k = 0; k < 128; k += 8)
#pragma unroll
            for (int u2 = 0; u2 < 8; ++u2)
                acc += Apt[k + u2] * Wp[(size_t)(k + u2) * M0_];
        red[ks][cl] = acc;
        __syncthreads();
        if (ks == 0) {
            float s = red[0][cl] + red[1][cl] + red[2][cl] + red[3][cl] + bm1[c];
            s1[c] = fmaxf(s, 0.f);
        }
        __syncthreads();
    }
    // stage 2: 128 outs, K=256 (kper=64)
    float s2v[2];
    for (int cg = 0; cg < 2; ++cg) {
        int c = cg * 64 + cl;
        const float* Apt = s1 + ks * 64;
        const float* Wp  = Wm2 + (size_t)(ks * 64) * M1_ + c;
        float acc = 0.f;
        for (int k = 0; k < 64; k += 8)
#pragma unroll
            for (int u2 = 0; u2 < 8; ++u2)
                acc += Apt[k + u2] * Wp[(size_t)(k + u2) * M1_];
        red[ks][cl] = acc;
        __syncthreads();
        s2v[cg] = 0.f;
        if (ks == 0) {
            float s = red[0][cl] + red[1][cl] + red[2][cl] + red[3][cl] + bm2[c];
            s2v[cg] = fmaxf(s, 0.f);
        }
        __syncthreads();
    }
    if (ks == 0) { s0[cl] = s2v[0]; s0[64 + cl] = s2v[1]; }
    __syncthreads();
    // stage 3: 128 outs, K=128 (kper=32)
    for (int cg = 0; cg < 2; ++cg) {
        int c = cg * 64 + cl;
        const float* Apt = s0 + ks * 32;
        const float* Wp  = Wm3 + (size_t)(ks * 32) * C_ + c;
        float acc = 0.f;
        for (int k = 0; k < 32; k += 8)
#pragma unroll
            for (int u2 = 0; u2 < 8; ++u2)
                acc += Apt[k + u2] * Wp[(size_t)(k + u2) * C_];
        red[ks][cl] = acc;
        __syncthreads();
        if (ks == 0)
            out[(size_t)b * C_ + c] =
                red[0][cl] + red[1][cl] + red[2][cl] + red[3][cl] + bm3[c];
        __syncthreads();
    }
}

// ---------------- launch ----------------
extern "C" void kernel_launch(void* const* d_in, const int* in_sizes, int n_in,
                              void* d_out, int out_size, void* d_ws, size_t ws_size,
                              hipStream_t stream) {
    (void)in_sizes; (void)n_in; (void)out_size;
    if (ws_size < WS_SMALL) return;
    const bool big = (ws_size >= WS_BIG);

    const float* x    = (const float*)d_in[0];
    const float* Wf   = (const float*)d_in[2];
    const float* bfv  = (const float*)d_in[3];
    const float* Wnn  = (const float*)d_in[4];
    const float* bnn  = (const float*)d_in[5];
    const float* g1   = (const float*)d_in[6];
    const float* b1   = (const float*)d_in[7];
    const float* We   = (const float*)d_in[8];
    const float* be   = (const float*)d_in[9];
    const float* g2   = (const float*)d_in[10];
    const float* b2   = (const float*)d_in[11];
    const float* Wl   = (const float*)d_in[12];
    const float* bl   = (const float*)d_in[13];
    const float* alpha= (const float*)d_in[14];
    const float* gg   = (const float*)d_in[15];
    const float* bgb  = (const float*)d_in[16];
    const float* Wg   = (const float*)d_in[17];
    const float* bg2  = (const float*)d_in[18];
    const float* Wm1  = (const float*)d_in[19];
    const float* bm1  = (const float*)d_in[20];
    const float* Wm2  = (const float*)d_in[21];
    const float* bm2  = (const float*)d_in[22];
    const float* Wm3  = (const float*)d_in[23];
    const float* bm3  = (const float*)d_in[24];
    float* outp = (float*)d_out;

    char* ws = (char*)d_ws;
    float*    h    = (float*)(ws + OFF_H);
    ushort_t* Ap   = (ushort_t*)(ws + OFF_APACK);
    ushort_t* Qpk  = (ushort_t*)(ws + OFF_WPK);
    float*    bcatA= (float*)(ws + OFF_BCA);
    double*   sta  = (double*)(ws + OFF_STA);
    float*    sqb  = (float*)(ws + OFF_SQ);
    int*      idxb = (int*)  (ws + OFF_IDX);

    size_t offD = big ? OFF_DBIG : OFF_DSML;
    float*    dmat = (float*)(ws + offD);
    float*    t    = (float*)(ws + offD);                      // overlays D (dead)
    float*    uv   = big ? (float*)(ws + OFF_UVBIG)
                         : (float*)(ws + offD + (size_t)50331648);
    float*    pmax = (float*)(ws + offD + (size_t)84672512);   // overlays D (dead)

    ushort_t* Qwnn = Qpk + (size_t)WPK_WNN * KPC_;
    ushort_t* Qwg  = Qpk + (size_t)WPK_WG  * KPC_;

    // fused prep: feat+pack | weight packs | stats zero
    hipLaunchKernelGGL(prep, dim3(BN_ + 3840 + 9), dim3(256), 0, stream,
                       x, Wf, bfv, h, Ap, Wnn, Wl, Wg, We, be, Qpk, bcatA, sta);

    // t = h@Wnn+bnn via MFMA (t-stats -> slot 0), XCD-pinned
    hipLaunchKernelGGL(mfma_gemm, dim3(256), dim3(256), 0, stream,
                       Ap, Qwnn, bnn, t, H_, 0,
                       (const float*)nullptr, (const float*)nullptr, 0, sta, 2);

    for (int l = 0; l < L_; ++l) {
        const float* src1 = (l == 0) ? t : h;
        hipLaunchKernelGGL(bn_apply_pack, dim3(BN_ / 8), dim3(256), 0, stream,
                           src1, sta + (size_t)(2 * l) * 512,
                           g1 + l * H_, b1 + l * H_, Ap, sqb);
        if (big) {
            // fused: gram (off-diag first, diag last) + uv gemm tail-filler
            hipLaunchKernelGGL(gram_uv, dim3(1600), dim3(256), GRAM_LDS, stream,
                               Ap, sqb, dmat,
                               Qpk + (size_t)(WPK_QCAT + l * 512) * KPC_,
                               bcatA + (size_t)l * 512, uv);
            hipLaunchKernelGGL(topk16, dim3(BN_ / 4), dim3(256), 0, stream, dmat, idxb);
        } else {
            hipLaunchKernelGGL(gram_sym, dim3(1088), dim3(256), GRAM_LDS, stream,
                               Ap, sqb, dmat);
            hipLaunchKernelGGL(topk16, dim3(BN_ / 4), dim3(256), 0, stream, dmat, idxb);
            hipLaunchKernelGGL(mfma_gemm, dim3(512), dim3(256), 0, stream,
                               Ap, Qpk + (size_t)(WPK_QCAT + l * 512) * KPC_,
                               bcatA + (size_t)l * 512, uv, 512, 0,
                               (const float*)nullptr, (const float*)nullptr, 0,
                               (double*)nullptr, 4);
        }
        hipLaunchKernelGGL(gather_max, dim3(512), dim3(256), 0, stream,
                           uv, idxb, t, sta + (size_t)(2 * l + 1) * 512);
        hipLaunchKernelGGL(bn_apply_pack, dim3(BN_ / 8), dim3(256), 0, stream,
                           t, sta + (size_t)(2 * l + 1) * 512,
                           g2 + l * H_, b2 + l * H_, Ap, (float*)nullptr);
        hipLaunchKernelGGL(mfma_gemm, dim3(256), dim3(256), 0, stream,
                           Ap, Qpk + (size_t)(WPK_WL + l * 256) * KPC_,
                           bl + (size_t)l * H_, h, H_, 2,
                           h, alpha, l, sta + (size_t)(2 * l + 2) * 512, 2);
    }

    // head: BN from slot 8, pack, fused Wg-gemm+pool, fused pool2+MLP
    hipLaunchKernelGGL(bn_apply_pack, dim3(BN_ / 8), dim3(256), 0, stream,
                       h, sta + (size_t)8 * 512, gg, bgb, Ap, (float*)nullptr);
    hipLaunchKernelGGL(head_gemm_pool, dim3(512), dim3(256), 0, stream,
                       Ap, Qwg, bg2, pmax);
    hipLaunchKernelGGL(head3, dim3(8), dim3(256), 0, stream,
                       pmax, Wm1, bm1, Wm2, bm2, Wm3, bm3, outp);
}